// Round 2
// baseline (1208.671 us; speedup 1.0000x reference)
//
#include <hip/hip_runtime.h>

#define NTHREADS 256
#define NB 2        // nodes per block (N=50000 -> 25000 blocks, no tail)
#define K 16
#define KP1 17
#define F 128
#define H 8
#define D 64
#define FP 132      // padded row stride: rows land 4 banks apart; k,k+8 alias = 2-way (free)
#define NEG_SLOPE 0.2f

// LDS: xall 2*17*132*4 = 17952 + attn 2*17*8*4 = 1088 + self 64 = 19104 B -> 8 blocks/CU
// 8 blocks * 4 waves = 32 waves/CU = 100% occupancy. Needs VGPR <= 64 -> __launch_bounds__(256,8).

__global__ __launch_bounds__(NTHREADS, 8) void gat_kernel(
    const float* __restrict__ x_self,   // [N,F]
    const float* __restrict__ x_neigh,  // [N,K,F]
    const float* __restrict__ W,        // [H,F,D]
    const float* __restrict__ a_self,   // [H,F]
    const float* __restrict__ a_neigh,  // [H,F]
    float* __restrict__ out,            // [N,H*D]
    int N)
{
    __shared__ __align__(16) float xall[NB][KP1][FP];   // k=0 is self row; reused as yb after phase 4
    __shared__ __align__(16) float attn[NB][KP1][H];
    __shared__ float self_s[NB][H];

    float* yb = (float*)xall;   // [NB][H][FP] alias, valid after phase-4 second sync

    const int tid = threadIdx.x;
    const int node0 = blockIdx.x * NB;

    // ---- Phase 1: stage x_all into LDS (float4, coalesced) ----
    {
        const int tot_self = NB * (F / 4);              // 64 float4
        for (int i = tid; i < tot_self; i += NTHREADS) {
            int nb = i / (F / 4);
            int f4 = i % (F / 4);
            if (node0 + nb < N) {
                float4 v = ((const float4*)(x_self + (size_t)(node0 + nb) * F))[f4];
                *(float4*)&xall[nb][0][f4 * 4] = v;
            }
        }
        const int tot_n = NB * K * (F / 4);             // 1024 float4
        for (int i = tid; i < tot_n; i += NTHREADS) {
            int nb  = i / (K * F / 4);
            int rem = i % (K * F / 4);
            int k   = rem / (F / 4);
            int f4  = rem % (F / 4);
            if (node0 + nb < N) {
                float4 v = ((const float4*)(x_neigh + ((size_t)(node0 + nb) * K + k) * F))[f4];
                *(float4*)&xall[nb][k + 1][f4 * 4] = v;
            }
        }
    }
    __syncthreads();

    // ---- Phase 2: unified logit dots. 288 tasks = NB * (17*8 neigh-dots + 8 self-dots) ----
    {
        const int TPN = KP1 * H + H;                    // 144 tasks per node
        for (int i = tid; i < NB * TPN; i += NTHREADS) {
            int nb  = i / TPN;
            int rem = i % TPN;
            int k, h;
            const float* av;
            const float* xr;
            bool is_self = (rem >= KP1 * H);
            if (!is_self) {
                k = rem >> 3; h = rem & 7;
                av = a_neigh + h * F;
                xr = &xall[nb][k][0];
            } else {
                k = 0; h = rem - KP1 * H;
                av = a_self + h * F;
                xr = &xall[nb][0][0];
            }
            float4 s = {0.f, 0.f, 0.f, 0.f};
            #pragma unroll 4
            for (int f4 = 0; f4 < F / 4; f4++) {
                float4 xv = *(const float4*)(xr + f4 * 4);
                float4 avv = ((const float4*)av)[f4];
                s.x += xv.x * avv.x; s.y += xv.y * avv.y;
                s.z += xv.z * avv.z; s.w += xv.w * avv.w;
            }
            float dot = (s.x + s.y) + (s.z + s.w);
            if (!is_self) attn[nb][k][h] = dot;
            else          self_s[nb][h] = dot;
        }
    }
    __syncthreads();

    // ---- Phase 3: add self logit, LeakyReLU, exp; store 1/sum in self_s.
    //      Normalization folded into phase 4. Only 16 lanes active; other resident
    //      blocks (8/CU) hide this. ----
    for (int i = tid; i < NB * H; i += NTHREADS) {
        int nb = i >> 3, h = i & 7;
        float sl = self_s[nb][h];
        float lg[KP1];
        float m = -1e30f;
        #pragma unroll
        for (int k = 0; k < KP1; k++) {
            float v = sl + attn[nb][k][h];
            v = (v >= 0.f) ? v : NEG_SLOPE * v;
            lg[k] = v;
            m = fmaxf(m, v);
        }
        float s = 0.f;
        #pragma unroll
        for (int k = 0; k < KP1; k++) {
            float e = __expf(lg[k] - m);
            attn[nb][k][h] = e;
            s += e;
        }
        self_s[nb][h] = 1.0f / s;    // reuse as inverse-denominator
    }
    __syncthreads();

    // ---- Phase 4: y[nb][h][f] = inv_s * sum_k e[k,h] * x_all[k][f].
    //      Thread = (f4, nb, head-pair): each xall float4 read ONCE, applied to 2 heads
    //      via one 8B attn read. Per-half-wave xv read covers all 32 banks (conflict-free);
    //      attn reads are broadcast. ----
    {
        const int f4 = tid & 31;         // 0..31
        const int nb = (tid >> 5) & 1;   // 0..1
        const int hh = tid >> 6;         // 0..3 -> heads hh*2, hh*2+1
        const float* xb = &xall[nb][0][f4 * 4];
        const float* ab = &attn[nb][0][hh * 2];
        float4 a0 = {0.f,0.f,0.f,0.f}, a1 = a0;
        #pragma unroll 4
        for (int k = 0; k < KP1; k++) {
            float4 xv = *(const float4*)(xb + k * FP);
            float2 av = *(const float2*)(ab + k * H);
            a0.x += av.x * xv.x; a0.y += av.x * xv.y; a0.z += av.x * xv.z; a0.w += av.x * xv.w;
            a1.x += av.y * xv.x; a1.y += av.y * xv.y; a1.z += av.y * xv.z; a1.w += av.y * xv.w;
        }
        const float i0 = self_s[nb][hh * 2 + 0];
        const float i1 = self_s[nb][hh * 2 + 1];
        a0.x *= i0; a0.y *= i0; a0.z *= i0; a0.w *= i0;
        a1.x *= i1; a1.y *= i1; a1.z *= i1; a1.w *= i1;
        __syncthreads();   // everyone done READING xall
        *(float4*)&yb[((size_t)(nb * H) + hh * 2 + 0) * FP + f4 * 4] = a0;
        *(float4*)&yb[((size_t)(nb * H) + hh * 2 + 1) * FP + f4 * 4] = a1;
    }
    __syncthreads();

    // ---- Phase 5: out[nb][h][d] = y[nb][h][:] @ W[h][:][d].
    //      Thread = (d-pair, h): float2 W loads (wave reads h and h+... two 256B segments),
    //      y reads are LDS broadcasts, float2 stores give 512B contiguous per wave. ----
    {
        const int d2 = tid & 31;         // covers d = d2*2, d2*2+1
        const int h  = tid >> 5;         // 0..7
        const float* Wp = W + ((size_t)h * F) * D + d2 * 2;
        const float* y0 = &yb[((size_t)(0 * H) + h) * FP];
        const float* y1 = &yb[((size_t)(1 * H) + h) * FP];
        float2 c0 = {0.f,0.f}, c1 = c0;
        #pragma unroll 4
        for (int f4 = 0; f4 < F / 4; f4++) {
            float2 w0 = *(const float2*)(Wp + (f4 * 4 + 0) * D);
            float2 w1 = *(const float2*)(Wp + (f4 * 4 + 1) * D);
            float2 w2 = *(const float2*)(Wp + (f4 * 4 + 2) * D);
            float2 w3 = *(const float2*)(Wp + (f4 * 4 + 3) * D);
            float4 v0 = *(const float4*)(y0 + f4 * 4);
            float4 v1 = *(const float4*)(y1 + f4 * 4);
            c0.x += v0.x * w0.x + v0.y * w1.x + v0.z * w2.x + v0.w * w3.x;
            c0.y += v0.x * w0.y + v0.y * w1.y + v0.z * w2.y + v0.w * w3.y;
            c1.x += v1.x * w0.x + v1.y * w1.x + v1.z * w2.x + v1.w * w3.x;
            c1.y += v1.x * w0.y + v1.y * w1.y + v1.z * w2.y + v1.w * w3.y;
        }
        if (node0 + 0 < N) *(float2*)&out[(size_t)(node0 + 0) * (H * D) + h * D + d2 * 2] = c0;
        if (node0 + 1 < N) *(float2*)&out[(size_t)(node0 + 1) * (H * D) + h * D + d2 * 2] = c1;
    }
}

extern "C" void kernel_launch(void* const* d_in, const int* in_sizes, int n_in,
                              void* d_out, int out_size, void* d_ws, size_t ws_size,
                              hipStream_t stream) {
    const float* x_self  = (const float*)d_in[0];
    const float* x_neigh = (const float*)d_in[1];
    const float* W       = (const float*)d_in[2];
    const float* a_self  = (const float*)d_in[3];
    const float* a_neigh = (const float*)d_in[4];
    float* out = (float*)d_out;

    const int N = in_sizes[0] / F;                 // 50000
    const int nblocks = (N + NB - 1) / NB;         // 25000
    gat_kernel<<<nblocks, NTHREADS, 0, stream>>>(x_self, x_neigh, W, a_self, a_neigh, out, N);
}

// Round 3
// 842.209 us; speedup vs baseline: 1.4351x; 1.4351x over previous
//
#include <hip/hip_runtime.h>

#define NTHREADS 256
#define NB 4        // nodes per block (N=50000 -> 12500 blocks, no tail)
#define K 16
#define KP1 17
#define F 128
#define H 8
#define D 64
#define FP 132      // padded xall row stride; P2 row groups land on distinct banks (2-way max = free)
#define NEG_SLOPE 0.2f

// LDS: xall 4*17*132*4 = 35904 + attn 4*17*8*4 = 2176 + self 128 = 38208 B -> 4 blocks/CU
// VGPR: __launch_bounds__(256,4) -> <=128 VGPR (4 waves/SIMD, 16 waves/CU).
// Round-0 structure (proven 620us). Changes: P2 pairs rows per task (halves a-vector VMEM,
// doubles per-thread acc chains); P5 fuses both heads + explicit 1-iter W prefetch.

__global__ __launch_bounds__(NTHREADS, 4) void gat_kernel(
    const float* __restrict__ x_self,   // [N,F]
    const float* __restrict__ x_neigh,  // [N,K,F]
    const float* __restrict__ W,        // [H,F,D]
    const float* __restrict__ a_self,   // [H,F]
    const float* __restrict__ a_neigh,  // [H,F]
    float* __restrict__ out,            // [N,H*D]
    int N)
{
    __shared__ __align__(16) float xall[NB][KP1][FP];   // k=0 is self row; reused as yb after phase 4
    __shared__ __align__(16) float attn[NB][KP1][H];
    __shared__ float self_s[NB][H];

    float* yb = (float*)xall;   // [NB][H][F] alias, valid after phase-4 second sync

    const int tid = threadIdx.x;
    const int node0 = blockIdx.x * NB;

    // ---- Phase 1: stage x_all into LDS (float4, coalesced) — round-0 exact ----
    {
        const int tot_self = NB * (F / 4);              // 128 float4
        for (int i = tid; i < tot_self; i += NTHREADS) {
            int nb = i / (F / 4);
            int f4 = i % (F / 4);
            if (node0 + nb < N) {
                float4 v = ((const float4*)(x_self + (size_t)(node0 + nb) * F))[f4];
                *(float4*)&xall[nb][0][f4 * 4] = v;
            }
        }
        const int tot_n = NB * K * (F / 4);             // 2048 float4
        for (int i = tid; i < tot_n; i += NTHREADS) {
            int nb  = i / (K * F / 4);
            int rem = i % (K * F / 4);
            int k   = rem / (F / 4);
            int f4  = rem % (F / 4);
            if (node0 + nb < N) {
                float4 v = ((const float4*)(x_neigh + ((size_t)(node0 + nb) * K + k) * F))[f4];
                *(float4*)&xall[nb][k + 1][f4 * 4] = v;
            }
        }
    }
    __syncthreads();

    // ---- Phase 2: logit dots, row-paired. 18 virtual rows per (nb,h):
    //      v=0..16 -> dot(xall[v], a_neigh[h]); v=17 -> dot(xall[0], a_self[h]).
    //      Pairs p=0..7 (rows 2p,2p+1) = 256 tasks, exactly one per thread: each a-vector
    //      float4 is loaded ONCE and used for two rows (halves a VMEM, 2 indep acc chains).
    //      Leftover pair (row16, self) handled by wave 0 (uniform branch for waves 1-3). ----
    {
        const int p  = tid & 7;          // rows 2p, 2p+1 (0..15)
        const int h  = (tid >> 3) & 7;
        const int nb = tid >> 6;
        const float* av  = a_neigh + h * F;
        const float* xr0 = &xall[nb][2 * p][0];
        const float* xr1 = &xall[nb][2 * p + 1][0];
        float4 s0 = {0.f, 0.f, 0.f, 0.f}, s1 = s0;
        #pragma unroll 8
        for (int f4 = 0; f4 < F / 4; f4++) {
            float4 avv = ((const float4*)av)[f4];
            float4 x0 = *(const float4*)(xr0 + f4 * 4);
            float4 x1 = *(const float4*)(xr1 + f4 * 4);
            s0.x += x0.x * avv.x; s0.y += x0.y * avv.y;
            s0.z += x0.z * avv.z; s0.w += x0.w * avv.w;
            s1.x += x1.x * avv.x; s1.y += x1.y * avv.y;
            s1.z += x1.z * avv.z; s1.w += x1.w * avv.w;
        }
        attn[nb][2 * p][h]     = (s0.x + s0.y) + (s0.z + s0.w);
        attn[nb][2 * p + 1][h] = (s1.x + s1.y) + (s1.z + s1.w);

        if (tid < 32) {                  // leftover: row 16 (a_neigh) + self row (a_self)
            const int h2  = tid & 7;
            const int nb2 = tid >> 3;
            const float* avn = a_neigh + h2 * F;
            const float* avs = a_self  + h2 * F;
            const float* x16 = &xall[nb2][16][0];
            const float* xs  = &xall[nb2][0][0];
            float4 t0 = {0.f, 0.f, 0.f, 0.f}, t1 = t0;
            #pragma unroll 8
            for (int f4 = 0; f4 < F / 4; f4++) {
                float4 an = ((const float4*)avn)[f4];
                float4 as = ((const float4*)avs)[f4];
                float4 v0 = *(const float4*)(x16 + f4 * 4);
                float4 v1 = *(const float4*)(xs  + f4 * 4);
                t0.x += v0.x * an.x; t0.y += v0.y * an.y;
                t0.z += v0.z * an.z; t0.w += v0.w * an.w;
                t1.x += v1.x * as.x; t1.y += v1.y * as.y;
                t1.z += v1.z * as.z; t1.w += v1.w * as.w;
            }
            attn[nb2][16][h2] = (t0.x + t0.y) + (t0.z + t0.w);
            self_s[nb2][h2]   = (t1.x + t1.y) + (t1.z + t1.w);
        }
    }
    __syncthreads();

    // ---- Phase 3: add self logit, LeakyReLU, softmax over k — round-0 exact ----
    for (int i = tid; i < NB * H; i += NTHREADS) {
        int nb = i >> 3, h = i & 7;
        float sl = self_s[nb][h];
        float m = -1e30f;
        #pragma unroll
        for (int k = 0; k < KP1; k++) {
            float lg = sl + attn[nb][k][h];
            lg = (lg >= 0.f) ? lg : NEG_SLOPE * lg;
            attn[nb][k][h] = lg;
            m = fmaxf(m, lg);
        }
        float s = 0.f;
        #pragma unroll
        for (int k = 0; k < KP1; k++) {
            float e = __expf(attn[nb][k][h] - m);
            attn[nb][k][h] = e;
            s += e;
        }
        float inv = 1.0f / s;
        #pragma unroll
        for (int k = 0; k < KP1; k++) attn[nb][k][h] *= inv;
    }
    __syncthreads();

    // ---- Phase 4: y[nb][h][f] = sum_k attn * x_all — round-0 exact ----
    {
        const int h  = (tid >> 5) & 7;   // 0..7
        const int f4 = tid & 31;         // 0..31
        float4 acc[NB];
        #pragma unroll
        for (int j = 0; j < NB; j++) acc[j] = {0.f, 0.f, 0.f, 0.f};
        for (int k = 0; k < KP1; k++) {
            #pragma unroll
            for (int j = 0; j < NB; j++) {
                float a = attn[j][k][h];
                float4 xv = *(const float4*)&xall[j][k][f4 * 4];
                acc[j].x += a * xv.x; acc[j].y += a * xv.y;
                acc[j].z += a * xv.z; acc[j].w += a * xv.w;
            }
        }
        __syncthreads();   // everyone done READING xall
        #pragma unroll
        for (int j = 0; j < NB; j++) {
            *(float4*)&yb[((size_t)j * H + h) * F + f4 * 4] = acc[j];
        }
    }
    __syncthreads();

    // ---- Phase 5: out[nb][h][d] = y[nb][h][:] @ W[h][:][d].
    //      tid -> d (0..63), head group hg (wave id); heads hg and hg+4 FUSED in one loop
    //      (8 independent acc chains) + explicit 1-iter W prefetch: next iter's 8 scalar
    //      W loads issue before this iter's 32 FMAs, hiding L2 latency under compute.
    //      y reads are LDS broadcasts (all 64 lanes same address). ----
    {
        const int d  = tid & (D - 1);
        const int hg = tid >> 6;         // wave id
        const float* Wp0 = W + ((size_t)hg * F) * D + d;
        const float* Wp1 = W + ((size_t)(hg + 4) * F) * D + d;
        const float* y00 = &yb[(size_t)(0 * H + hg) * F];
        const float* y01 = &yb[(size_t)(1 * H + hg) * F];
        const float* y02 = &yb[(size_t)(2 * H + hg) * F];
        const float* y03 = &yb[(size_t)(3 * H + hg) * F];
        const float* y10 = &yb[(size_t)(0 * H + hg + 4) * F];
        const float* y11 = &yb[(size_t)(1 * H + hg + 4) * F];
        const float* y12 = &yb[(size_t)(2 * H + hg + 4) * F];
        const float* y13 = &yb[(size_t)(3 * H + hg + 4) * F];

        float a00 = 0.f, a01 = 0.f, a02 = 0.f, a03 = 0.f;
        float a10 = 0.f, a11 = 0.f, a12 = 0.f, a13 = 0.f;

        // prefetch registers: current W values (8 scalars)
        float cw00 = Wp0[0 * D], cw01 = Wp0[1 * D], cw02 = Wp0[2 * D], cw03 = Wp0[3 * D];
        float cw10 = Wp1[0 * D], cw11 = Wp1[1 * D], cw12 = Wp1[2 * D], cw13 = Wp1[3 * D];

        #pragma unroll 4
        for (int f4 = 0; f4 < F / 4; f4++) {
            const int g = (f4 + 1) & 31;   // wrap at the end: harmless re-load of row 0
            // issue NEXT iteration's W loads first (in flight during the FMA block)
            float nw00 = Wp0[(g * 4 + 0) * D], nw01 = Wp0[(g * 4 + 1) * D];
            float nw02 = Wp0[(g * 4 + 2) * D], nw03 = Wp0[(g * 4 + 3) * D];
            float nw10 = Wp1[(g * 4 + 0) * D], nw11 = Wp1[(g * 4 + 1) * D];
            float nw12 = Wp1[(g * 4 + 2) * D], nw13 = Wp1[(g * 4 + 3) * D];

            float4 v00 = *(const float4*)(y00 + f4 * 4);
            float4 v01 = *(const float4*)(y01 + f4 * 4);
            float4 v02 = *(const float4*)(y02 + f4 * 4);
            float4 v03 = *(const float4*)(y03 + f4 * 4);
            float4 v10 = *(const float4*)(y10 + f4 * 4);
            float4 v11 = *(const float4*)(y11 + f4 * 4);
            float4 v12 = *(const float4*)(y12 + f4 * 4);
            float4 v13 = *(const float4*)(y13 + f4 * 4);

            a00 += v00.x * cw00 + v00.y * cw01 + v00.z * cw02 + v00.w * cw03;
            a01 += v01.x * cw00 + v01.y * cw01 + v01.z * cw02 + v01.w * cw03;
            a02 += v02.x * cw00 + v02.y * cw01 + v02.z * cw02 + v02.w * cw03;
            a03 += v03.x * cw00 + v03.y * cw01 + v03.z * cw02 + v03.w * cw03;
            a10 += v10.x * cw10 + v10.y * cw11 + v10.z * cw12 + v10.w * cw13;
            a11 += v11.x * cw10 + v11.y * cw11 + v11.z * cw12 + v11.w * cw13;
            a12 += v12.x * cw10 + v12.y * cw11 + v12.z * cw12 + v12.w * cw13;
            a13 += v13.x * cw10 + v13.y * cw11 + v13.z * cw12 + v13.w * cw13;

            cw00 = nw00; cw01 = nw01; cw02 = nw02; cw03 = nw03;
            cw10 = nw10; cw11 = nw11; cw12 = nw12; cw13 = nw13;
        }

        if (node0 + 0 < N) {
            out[(size_t)(node0 + 0) * (H * D) + hg * D + d] = a00;
            out[(size_t)(node0 + 0) * (H * D) + (hg + 4) * D + d] = a10;
        }
        if (node0 + 1 < N) {
            out[(size_t)(node0 + 1) * (H * D) + hg * D + d] = a01;
            out[(size_t)(node0 + 1) * (H * D) + (hg + 4) * D + d] = a11;
        }
        if (node0 + 2 < N) {
            out[(size_t)(node0 + 2) * (H * D) + hg * D + d] = a02;
            out[(size_t)(node0 + 2) * (H * D) + (hg + 4) * D + d] = a12;
        }
        if (node0 + 3 < N) {
            out[(size_t)(node0 + 3) * (H * D) + hg * D + d] = a03;
            out[(size_t)(node0 + 3) * (H * D) + (hg + 4) * D + d] = a13;
        }
    }
}

extern "C" void kernel_launch(void* const* d_in, const int* in_sizes, int n_in,
                              void* d_out, int out_size, void* d_ws, size_t ws_size,
                              hipStream_t stream) {
    const float* x_self  = (const float*)d_in[0];
    const float* x_neigh = (const float*)d_in[1];
    const float* W       = (const float*)d_in[2];
    const float* a_self  = (const float*)d_in[3];
    const float* a_neigh = (const float*)d_in[4];
    float* out = (float*)d_out;

    const int N = in_sizes[0] / F;                 // 50000
    const int nblocks = (N + NB - 1) / NB;         // 12500
    gat_kernel<<<nblocks, NTHREADS, 0, stream>>>(x_self, x_neigh, W, a_self, a_neigh, out, N);
}

// Round 4
// 782.618 us; speedup vs baseline: 1.5444x; 1.0761x over previous
//
#include <hip/hip_runtime.h>

#define NTHREADS 256
#define NB 4        // nodes per block (N=50000 -> 12500 blocks, no tail)
#define K 16
#define KP1 17
#define F 128
#define H 8
#define D 64
#define FP 132      // padded xall row stride; P2 row groups land on distinct banks (2-way max = free)
#define NEG_SLOPE 0.2f

// LDS: xall 4*17*132*4 = 35904 + attn 4*17*8*4 = 2176 + self 128 = 38208 B -> 4 blocks/CU
// VGPR: __launch_bounds__(256,4) -> <=128 VGPR (4 waves/SIMD, 16 waves/CU).
// Round-3 structure (proven 446us). Change: phase 5 re-mapped to (fg,d4) lanes ->
// float4 W loads + float4 y loads = 4x fewer VMEM and LDS instructions (TA-pipe was
// the phase-5 limiter), same FMA count, xor-shuffle reduce over fg groups.

__global__ __launch_bounds__(NTHREADS, 4) void gat_kernel(
    const float* __restrict__ x_self,   // [N,F]
    const float* __restrict__ x_neigh,  // [N,K,F]
    const float* __restrict__ W,        // [H,F,D]
    const float* __restrict__ a_self,   // [H,F]
    const float* __restrict__ a_neigh,  // [H,F]
    float* __restrict__ out,            // [N,H*D]
    int N)
{
    __shared__ __align__(16) float xall[NB][KP1][FP];   // k=0 is self row; reused as yb after phase 4
    __shared__ __align__(16) float attn[NB][KP1][H];
    __shared__ float self_s[NB][H];

    float* yb = (float*)xall;   // [NB][H][F] alias (stride F), valid after phase-4 second sync

    const int tid = threadIdx.x;
    const int node0 = blockIdx.x * NB;

    // ---- Phase 1: stage x_all into LDS (float4, coalesced) — round-3 exact ----
    {
        const int tot_self = NB * (F / 4);              // 128 float4
        for (int i = tid; i < tot_self; i += NTHREADS) {
            int nb = i / (F / 4);
            int f4 = i % (F / 4);
            if (node0 + nb < N) {
                float4 v = ((const float4*)(x_self + (size_t)(node0 + nb) * F))[f4];
                *(float4*)&xall[nb][0][f4 * 4] = v;
            }
        }
        const int tot_n = NB * K * (F / 4);             // 2048 float4
        for (int i = tid; i < tot_n; i += NTHREADS) {
            int nb  = i / (K * F / 4);
            int rem = i % (K * F / 4);
            int k   = rem / (F / 4);
            int f4  = rem % (F / 4);
            if (node0 + nb < N) {
                float4 v = ((const float4*)(x_neigh + ((size_t)(node0 + nb) * K + k) * F))[f4];
                *(float4*)&xall[nb][k + 1][f4 * 4] = v;
            }
        }
    }
    __syncthreads();

    // ---- Phase 2: logit dots, row-paired — round-3 exact ----
    {
        const int p  = tid & 7;          // rows 2p, 2p+1 (0..15)
        const int h  = (tid >> 3) & 7;
        const int nb = tid >> 6;
        const float* av  = a_neigh + h * F;
        const float* xr0 = &xall[nb][2 * p][0];
        const float* xr1 = &xall[nb][2 * p + 1][0];
        float4 s0 = {0.f, 0.f, 0.f, 0.f}, s1 = s0;
        #pragma unroll 8
        for (int f4 = 0; f4 < F / 4; f4++) {
            float4 avv = ((const float4*)av)[f4];
            float4 x0 = *(const float4*)(xr0 + f4 * 4);
            float4 x1 = *(const float4*)(xr1 + f4 * 4);
            s0.x += x0.x * avv.x; s0.y += x0.y * avv.y;
            s0.z += x0.z * avv.z; s0.w += x0.w * avv.w;
            s1.x += x1.x * avv.x; s1.y += x1.y * avv.y;
            s1.z += x1.z * avv.z; s1.w += x1.w * avv.w;
        }
        attn[nb][2 * p][h]     = (s0.x + s0.y) + (s0.z + s0.w);
        attn[nb][2 * p + 1][h] = (s1.x + s1.y) + (s1.z + s1.w);

        if (tid < 32) {                  // leftover: row 16 (a_neigh) + self row (a_self)
            const int h2  = tid & 7;
            const int nb2 = tid >> 3;
            const float* avn = a_neigh + h2 * F;
            const float* avs = a_self  + h2 * F;
            const float* x16 = &xall[nb2][16][0];
            const float* xs  = &xall[nb2][0][0];
            float4 t0 = {0.f, 0.f, 0.f, 0.f}, t1 = t0;
            #pragma unroll 8
            for (int f4 = 0; f4 < F / 4; f4++) {
                float4 an = ((const float4*)avn)[f4];
                float4 as = ((const float4*)avs)[f4];
                float4 v0 = *(const float4*)(x16 + f4 * 4);
                float4 v1 = *(const float4*)(xs  + f4 * 4);
                t0.x += v0.x * an.x; t0.y += v0.y * an.y;
                t0.z += v0.z * an.z; t0.w += v0.w * an.w;
                t1.x += v1.x * as.x; t1.y += v1.y * as.y;
                t1.z += v1.z * as.z; t1.w += v1.w * as.w;
            }
            attn[nb2][16][h2] = (t0.x + t0.y) + (t0.z + t0.w);
            self_s[nb2][h2]   = (t1.x + t1.y) + (t1.z + t1.w);
        }
    }
    __syncthreads();

    // ---- Phase 3: add self logit, LeakyReLU, softmax over k — round-3 exact ----
    for (int i = tid; i < NB * H; i += NTHREADS) {
        int nb = i >> 3, h = i & 7;
        float sl = self_s[nb][h];
        float m = -1e30f;
        #pragma unroll
        for (int k = 0; k < KP1; k++) {
            float lg = sl + attn[nb][k][h];
            lg = (lg >= 0.f) ? lg : NEG_SLOPE * lg;
            attn[nb][k][h] = lg;
            m = fmaxf(m, lg);
        }
        float s = 0.f;
        #pragma unroll
        for (int k = 0; k < KP1; k++) {
            float e = __expf(attn[nb][k][h] - m);
            attn[nb][k][h] = e;
            s += e;
        }
        float inv = 1.0f / s;
        #pragma unroll
        for (int k = 0; k < KP1; k++) attn[nb][k][h] *= inv;
    }
    __syncthreads();

    // ---- Phase 4: y[nb][h][f] = sum_k attn * x_all — round-3 exact ----
    {
        const int h  = (tid >> 5) & 7;   // 0..7
        const int f4 = tid & 31;         // 0..31
        float4 acc[NB];
        #pragma unroll
        for (int j = 0; j < NB; j++) acc[j] = {0.f, 0.f, 0.f, 0.f};
        for (int k = 0; k < KP1; k++) {
            #pragma unroll
            for (int j = 0; j < NB; j++) {
                float a = attn[j][k][h];
                float4 xv = *(const float4*)&xall[j][k][f4 * 4];
                acc[j].x += a * xv.x; acc[j].y += a * xv.y;
                acc[j].z += a * xv.z; acc[j].w += a * xv.w;
            }
        }
        __syncthreads();   // everyone done READING xall
        #pragma unroll
        for (int j = 0; j < NB; j++) {
            *(float4*)&yb[((size_t)j * H + h) * F + f4 * 4] = acc[j];
        }
    }
    __syncthreads();

    // ---- Phase 5 v3: out[nb][h][d] = y[nb][h][:] @ W[h][:][d].
    //      lane = (fg, d4): fg = lane>>4 picks f-phase (f = fb*16 + fg*4 + ff),
    //      d4 = lane&15 covers d = 4*d4..+3. Wave w handles heads w and w+4.
    //      Per fb-iter: 8 float4 y LDS reads (4 distinct 16B addrs, conflict-free,
    //      16-way broadcast) + 8 float4 W VMEM loads (4x256B segments) + 128 FMA.
    //      Total per wave: 64 LDS + 64 VMEM instrs (was 256 + 256).
    //      Tail: xor-shuffle reduce over fg groups (lanes sharing d4), then each
    //      fg group stores its own node as 16-lane contiguous float4 stores. ----
    {
        const int lane = tid & 63;
        const int w    = tid >> 6;          // wave id -> heads w, w+4
        const int fg   = lane >> 4;         // 0..3 f-phase
        const int d4   = lane & 15;         // d = d4*4 .. d4*4+3
        const int h0 = w, h1 = w + 4;
        const float* Wb0 = W + ((size_t)h0 * F) * D + d4 * 4;
        const float* Wb1 = W + ((size_t)h1 * F) * D + d4 * 4;

        float4 acc0[NB], acc1[NB];
        #pragma unroll
        for (int nb = 0; nb < NB; nb++) {
            acc0[nb] = {0.f, 0.f, 0.f, 0.f};
            acc1[nb] = {0.f, 0.f, 0.f, 0.f};
        }

        for (int fb = 0; fb < 8; fb++) {
            const int f0 = fb * 16 + fg * 4;       // this lane's 4 f values: f0..f0+3
            // W loads first (longest latency), 8 float4
            float4 w0[4], w1[4];
            #pragma unroll
            for (int ff = 0; ff < 4; ff++) {
                w0[ff] = *(const float4*)(Wb0 + (size_t)(f0 + ff) * D);
                w1[ff] = *(const float4*)(Wb1 + (size_t)(f0 + ff) * D);
            }
            // y loads, 8 float4 from LDS
            float4 y0[NB], y1[NB];
            #pragma unroll
            for (int nb = 0; nb < NB; nb++) {
                y0[nb] = *(const float4*)&yb[((size_t)nb * H + h0) * F + f0];
                y1[nb] = *(const float4*)&yb[((size_t)nb * H + h1) * F + f0];
            }
            #pragma unroll
            for (int nb = 0; nb < NB; nb++) {
                acc0[nb].x += y0[nb].x * w0[0].x + y0[nb].y * w0[1].x + y0[nb].z * w0[2].x + y0[nb].w * w0[3].x;
                acc0[nb].y += y0[nb].x * w0[0].y + y0[nb].y * w0[1].y + y0[nb].z * w0[2].y + y0[nb].w * w0[3].y;
                acc0[nb].z += y0[nb].x * w0[0].z + y0[nb].y * w0[1].z + y0[nb].z * w0[2].z + y0[nb].w * w0[3].z;
                acc0[nb].w += y0[nb].x * w0[0].w + y0[nb].y * w0[1].w + y0[nb].z * w0[2].w + y0[nb].w * w0[3].w;
                acc1[nb].x += y1[nb].x * w1[0].x + y1[nb].y * w1[1].x + y1[nb].z * w1[2].x + y1[nb].w * w1[3].x;
                acc1[nb].y += y1[nb].x * w1[0].y + y1[nb].y * w1[1].y + y1[nb].z * w1[2].y + y1[nb].w * w1[3].y;
                acc1[nb].z += y1[nb].x * w1[0].z + y1[nb].y * w1[1].z + y1[nb].z * w1[2].z + y1[nb].w * w1[3].z;
                acc1[nb].w += y1[nb].x * w1[0].w + y1[nb].y * w1[1].w + y1[nb].z * w1[2].w + y1[nb].w * w1[3].w;
            }
        }

        // reduce over the 4 fg groups (lanes l, l^16, l^32, l^48 share d4)
        #pragma unroll
        for (int nb = 0; nb < NB; nb++) {
            acc0[nb].x += __shfl_xor(acc0[nb].x, 16); acc0[nb].x += __shfl_xor(acc0[nb].x, 32);
            acc0[nb].y += __shfl_xor(acc0[nb].y, 16); acc0[nb].y += __shfl_xor(acc0[nb].y, 32);
            acc0[nb].z += __shfl_xor(acc0[nb].z, 16); acc0[nb].z += __shfl_xor(acc0[nb].z, 32);
            acc0[nb].w += __shfl_xor(acc0[nb].w, 16); acc0[nb].w += __shfl_xor(acc0[nb].w, 32);
            acc1[nb].x += __shfl_xor(acc1[nb].x, 16); acc1[nb].x += __shfl_xor(acc1[nb].x, 32);
            acc1[nb].y += __shfl_xor(acc1[nb].y, 16); acc1[nb].y += __shfl_xor(acc1[nb].y, 32);
            acc1[nb].z += __shfl_xor(acc1[nb].z, 16); acc1[nb].z += __shfl_xor(acc1[nb].z, 32);
            acc1[nb].w += __shfl_xor(acc1[nb].w, 16); acc1[nb].w += __shfl_xor(acc1[nb].w, 32);
        }

        // each fg group stores node nb == fg (16 lanes x 16B = 256B contiguous per store)
        #pragma unroll
        for (int nb = 0; nb < NB; nb++) {
            if (fg == nb && node0 + nb < N) {
                *(float4*)&out[(size_t)(node0 + nb) * (H * D) + h0 * D + d4 * 4] = acc0[nb];
                *(float4*)&out[(size_t)(node0 + nb) * (H * D) + h1 * D + d4 * 4] = acc1[nb];
            }
        }
    }
}

extern "C" void kernel_launch(void* const* d_in, const int* in_sizes, int n_in,
                              void* d_out, int out_size, void* d_ws, size_t ws_size,
                              hipStream_t stream) {
    const float* x_self  = (const float*)d_in[0];
    const float* x_neigh = (const float*)d_in[1];
    const float* W       = (const float*)d_in[2];
    const float* a_self  = (const float*)d_in[3];
    const float* a_neigh = (const float*)d_in[4];
    float* out = (float*)d_out;

    const int N = in_sizes[0] / F;                 // 50000
    const int nblocks = (N + NB - 1) / NB;         // 12500
    gat_kernel<<<nblocks, NTHREADS, 0, stream>>>(x_self, x_neigh, W, a_self, a_neigh, out, N);
}